// Round 3
// baseline (234.183 us; speedup 1.0000x reference)
//
#include <hip/hip_runtime.h>
#include <hip/hip_bf16.h>

typedef unsigned short u16;
typedef __attribute__((ext_vector_type(8))) short short8;
typedef __attribute__((ext_vector_type(4))) float f32x4;

constexpr int N = 8192;
constexpr int D = 1024;
constexpr float INVT = 1.0f / 0.07f;
constexpr int BK = 64;
constexpr int KT = D / BK;                     // 16 K-tiles
constexpr int NBLK = 32;                       // 8192 / 256 row-blocks
constexpr int NTRI = NBLK * (NBLK + 1) / 2;    // 528 lower-tri tiles (8 | 528)

// ---- workspace layout (bytes) ----
constexpr size_t OFF_FBF  = 0;                       // N*D bf16 = 16 MiB
constexpr size_t OFF_SUME = 16777216;                // N f32 (32 KiB)
constexpr size_t OFF_POSS = OFF_SUME + 32768;        // N f32 (32 KiB)
constexpr size_t OFF_HIST = OFF_POSS + 32768;        // 32 i32 (pad 128)
constexpr size_t OFF_TYPE = OFF_HIST + 128;          // N i32 (32 KiB)
constexpr int ZERO_WORDS = (32768 + 32768 + 128) / 4;

__global__ __launch_bounds__(256) void k_zero(float* __restrict__ p, int n) {
  int i = blockIdx.x * 256 + threadIdx.x;
  if (i < n) p[i] = 0.0f;
}

__device__ __forceinline__ u16 f2bf(float f) {
  __hip_bfloat16 h = __float2bfloat16(f);
  union { __hip_bfloat16 h; u16 u; } cv; cv.h = h; return cv.u;
}

// one wave per row: 4 rows/block, no cross-wave sync
__global__ __launch_bounds__(256) void k_norm(
    const float* __restrict__ feat, const long long* __restrict__ et,
    u16* __restrict__ fbf, int* __restrict__ types, int* __restrict__ hist) {
  const int row = blockIdx.x * 4 + (threadIdx.x >> 6);
  const int l = threadIdx.x & 63;
  const float4* src = (const float4*)(feat + (size_t)row * D);
  float4 v[4];
  float ss = 0.f;
  #pragma unroll
  for (int c = 0; c < 4; ++c) {
    v[c] = src[c * 64 + l];
    ss += v[c].x * v[c].x + v[c].y * v[c].y + v[c].z * v[c].z + v[c].w * v[c].w;
  }
  #pragma unroll
  for (int m = 32; m; m >>= 1) ss += __shfl_xor(ss, m);
  const float sc = 1.0f / fmaxf(sqrtf(ss), 1e-12f);
  ushort4* dst = (ushort4*)(fbf + (size_t)row * D);
  #pragma unroll
  for (int c = 0; c < 4; ++c) {
    ushort4 o;
    o.x = f2bf(v[c].x * sc); o.y = f2bf(v[c].y * sc);
    o.z = f2bf(v[c].z * sc); o.w = f2bf(v[c].w * sc);
    dst[c * 64 + l] = o;
  }
  if (l == 0) {
    int ty = (int)et[row];
    types[row] = ty;
    atomicAdd(&hist[ty], 1);
  }
}

__device__ __forceinline__ void async_ld16(const u16* g, u16* l) {
  __builtin_amdgcn_global_load_lds(
      (const __attribute__((address_space(1))) void*)g,
      (__attribute__((address_space(3))) void*)l, 16, 0, 0);
}

__device__ __forceinline__ void mfma16(f32x4& d, short8 a, short8 b) {
  asm volatile("v_mfma_f32_16x16x32_bf16 %0, %1, %2, %0"
               : "+v"(d) : "v"(a), "v"(b));
}

__device__ __forceinline__ short8 rd(const u16* m, int byte) {
  return *(const short8*)(m + (byte >> 1));
}

// 256x256 lower-tri tiles of sim = fbf*fbf^T/T; counted-vmcnt phase schedule.
// 8 waves (2Mx4N), per-wave 128x64 out = 8x4 frags of 16x16x32 MFMA. BK=64.
// Per K-tile: 4 phases x 16 MFMA; next tile's 8 global_load_lds issued in
// phases 0-1 (other buffer), single vmcnt(0) at end of phase 3 (~2.5-phase
// slack -> no young-load stall). T2 swizzle: byte bits4-6 ^= row&7, applied
// as pre-swizzled GLOBAL source + swizzled ds_read (LDS dest stays linear).
__global__ __launch_bounds__(512, 2) void k_gemm(
    const u16* __restrict__ fbf, const int* __restrict__ types,
    float* __restrict__ sum_exp, float* __restrict__ pos_sum) {
  __shared__ u16 As[2][256 * 64];   // 64 KiB
  __shared__ u16 Bs[2][256 * 64];   // 64 KiB
  __shared__ int rt[256], ct[256];

  const int pid = blockIdx.x;
  const int x = (pid & 7) * (NTRI / 8) + (pid >> 3);   // bijective XCD swizzle
  int rb = (int)((sqrtf(8.0f * (float)x + 1.0f) - 1.0f) * 0.5f);
  while ((rb + 1) * (rb + 2) / 2 <= x) ++rb;
  while (rb * (rb + 1) / 2 > x) --rb;
  const int cb = x - rb * (rb + 1) / 2;
  const int brow = rb * 256, bcol = cb * 256;
  const bool diag = (rb == cb);

  const int tid = threadIdx.x;
  const int lane = tid & 63;
  const int wid = tid >> 6;
  const int wr = wid >> 2;   // 0..1 (M)
  const int wc = wid & 3;    // 0..3 (N)

  if (tid < 256) rt[tid] = types[brow + tid];
  else           ct[tid - 256] = types[bcol + tid - 256];

  f32x4 acc[8][4];
  #pragma unroll
  for (int i = 0; i < 8; ++i)
    #pragma unroll
    for (int j = 0; j < 4; ++j) acc[i][j] = (f32x4){0.f, 0.f, 0.f, 0.f};

  // ---- staging map: instr j covers LDS bytes [j*8192 + tid*16) of one
  // 256x64 tile; row = j*64 + (tid>>3); 16B slot pre-swizzled in SOURCE.
  const int srow = tid >> 3;                      // 0..63
  const int scol = (((tid & 7) ^ (srow & 7))) * 8;
  const u16* gA = fbf + (size_t)(brow + srow) * D + scol;
  const u16* gB = fbf + (size_t)(bcol + srow) * D + scol;
  const int lbase = wid * 512;                    // + j*4096 per instr (elems)

  // ---- fragment read offsets (bytes), with matching XOR swizzle.
  // row&7 == lane&7 for all frags (row = base16k + (lane&15), base16k%16==0)
  const int l15 = lane & 15;
  const int sw = (lane & 7) << 4;
  const int k16 = (lane >> 4) << 4;
  const int rowAb = (wr * 128 + l15) * 128;       // + mi*2048
  const int rowBb = (wc * 64 + l15) * 128;        // + ni*2048

  #define ABYTE(mi, kk) (rowAb + (mi) * 2048 + ((((kk) << 6) + k16) ^ sw))
  #define BBYTE(ni, kk) (rowBb + (ni) * 2048 + ((((kk) << 6) + k16) ^ sw))

  // prologue: stage K-tile 0 into buf 0; full drain + publish rt/ct
  #pragma unroll
  for (int j = 0; j < 4; ++j) {
    async_ld16(gA + (size_t)j * 64 * D, (u16*)As[0] + j * 4096 + lbase);
    async_ld16(gB + (size_t)j * 64 * D, (u16*)Bs[0] + j * 4096 + lbase);
  }
  __syncthreads();

  #define BAR() __builtin_amdgcn_s_barrier()
  #define MFMA_PAIR(m0, m1)                                          \
    __builtin_amdgcn_s_setprio(1);                                   \
    _Pragma("unroll")                                                \
    for (int ni = 0; ni < 4; ++ni) {                                 \
      mfma16(acc[m0][ni], a0[0], b[ni][0]);                          \
      mfma16(acc[m0][ni], a0[1], b[ni][1]);                          \
      mfma16(acc[m1][ni], a1[0], b[ni][0]);                          \
      mfma16(acc[m1][ni], a1[1], b[ni][1]);                          \
    }                                                                \
    __builtin_amdgcn_s_setprio(0);

  for (int kt = 0; kt < KT; ++kt) {
    const u16* Ac = As[kt & 1];
    const u16* Bc = Bs[kt & 1];
    u16* An = (u16*)As[(kt & 1) ^ 1];
    u16* Bn = (u16*)Bs[(kt & 1) ^ 1];
    const int ko2 = (kt + 1) * BK;
    const bool more = (kt + 1 < KT);
    short8 b[4][2], a0[2], a1[2];

    // ---- phase 0: stage A(kt+1); read all B-frags + A mi{0,1}
    if (more) {
      #pragma unroll
      for (int j = 0; j < 4; ++j)
        async_ld16(gA + (size_t)j * 64 * D + ko2, An + j * 4096 + lbase);
    }
    #pragma unroll
    for (int ni = 0; ni < 4; ++ni) {
      b[ni][0] = rd(Bc, BBYTE(ni, 0));
      b[ni][1] = rd(Bc, BBYTE(ni, 1));
    }
    a0[0] = rd(Ac, ABYTE(0, 0)); a0[1] = rd(Ac, ABYTE(0, 1));
    a1[0] = rd(Ac, ABYTE(1, 0)); a1[1] = rd(Ac, ABYTE(1, 1));
    BAR();
    MFMA_PAIR(0, 1)
    BAR();

    // ---- phase 1: stage B(kt+1); A mi{2,3}
    if (more) {
      #pragma unroll
      for (int j = 0; j < 4; ++j)
        async_ld16(gB + (size_t)j * 64 * D + ko2, Bn + j * 4096 + lbase);
    }
    a0[0] = rd(Ac, ABYTE(2, 0)); a0[1] = rd(Ac, ABYTE(2, 1));
    a1[0] = rd(Ac, ABYTE(3, 0)); a1[1] = rd(Ac, ABYTE(3, 1));
    BAR();
    MFMA_PAIR(2, 3)
    BAR();

    // ---- phase 2: A mi{4,5}
    a0[0] = rd(Ac, ABYTE(4, 0)); a0[1] = rd(Ac, ABYTE(4, 1));
    a1[0] = rd(Ac, ABYTE(5, 0)); a1[1] = rd(Ac, ABYTE(5, 1));
    BAR();
    MFMA_PAIR(4, 5)
    BAR();

    // ---- phase 3: A mi{6,7}; drain next-tile loads (issued >=2 phases ago)
    a0[0] = rd(Ac, ABYTE(6, 0)); a0[1] = rd(Ac, ABYTE(6, 1));
    a1[0] = rd(Ac, ABYTE(7, 0)); a1[1] = rd(Ac, ABYTE(7, 1));
    BAR();
    MFMA_PAIR(6, 7)
    asm volatile("s_waitcnt vmcnt(0)" ::: "memory");
    BAR();
  }

  // MFMA -> VALU read hazard guard (inline-asm MFMA opaque to hazard recog.)
  asm volatile("s_nop 7\n\ts_nop 7\n\ts_nop 7");
  #pragma unroll
  for (int i = 0; i < 8; ++i)
    #pragma unroll
    for (int j = 0; j < 4; ++j) asm volatile("" : "+v"(acc[i][j]));

  // epilogue: C/D layout col = lane&15, row = (lane>>4)*4 + reg  [m89]
  const int csub = lane & 15;
  const int rsub = (lane >> 4) * 4;
  int gcolv[4], ctv[4];
  #pragma unroll
  for (int ni = 0; ni < 4; ++ni) {
    const int cl = wc * 64 + ni * 16 + csub;
    gcolv[ni] = bcol + cl;
    ctv[ni] = ct[cl];
  }
  float cse[4] = {0.f, 0.f, 0.f, 0.f};
  float cps[4] = {0.f, 0.f, 0.f, 0.f};

  #pragma unroll
  for (int mi = 0; mi < 8; ++mi) {
    #pragma unroll
    for (int r = 0; r < 4; ++r) {
      const int rl = wr * 128 + mi * 16 + rsub + r;
      const int grow = brow + rl;
      const int rty = rt[rl];
      float se = 0.f, ps = 0.f;
      #pragma unroll
      for (int ni = 0; ni < 4; ++ni) {
        const float s = acc[mi][ni][r] * INVT;
        const float e = __expf(s);
        const bool match = (ctv[ni] == rty);
        if (diag) {
          if (gcolv[ni] != grow) { se += e; if (match) ps += s; }
        } else {
          se += e; if (match) ps += s;
          cse[ni] += e; if (match) cps[ni] += s;   // transpose -> row gcolv[ni]
        }
      }
      #pragma unroll
      for (int m = 8; m; m >>= 1) {
        se += __shfl_xor(se, m);
        ps += __shfl_xor(ps, m);
      }
      if (csub == 0) {
        atomicAdd(&sum_exp[grow], se);
        atomicAdd(&pos_sum[grow], ps);
      }
    }
  }

  if (!diag) {
    #pragma unroll
    for (int ni = 0; ni < 4; ++ni) {
      float se = cse[ni], ps = cps[ni];
      se += __shfl_xor(se, 16); se += __shfl_xor(se, 32);
      ps += __shfl_xor(ps, 16); ps += __shfl_xor(ps, 32);
      if (lane < 16) {
        atomicAdd(&sum_exp[gcolv[ni]], se);
        atomicAdd(&pos_sum[gcolv[ni]], ps);
      }
    }
  }
}

__global__ __launch_bounds__(1024) void k_final(
    const float* __restrict__ sum_exp, const float* __restrict__ pos_sum,
    const int* __restrict__ types, const int* __restrict__ hist,
    float* __restrict__ out) {
  const int t = threadIdx.x;
  float ls = 0.f, cnt = 0.f;
  for (int r = t; r < N; r += 1024) {
    const int pc = hist[types[r]] - 1;
    if (pc > 0) {
      const float pm = pos_sum[r] / (float)pc;
      ls += -logf(__expf(pm) / sum_exp[r] + 1e-10f);
      cnt += 1.f;
    }
  }
  #pragma unroll
  for (int m = 32; m; m >>= 1) {
    ls += __shfl_xor(ls, m);
    cnt += __shfl_xor(cnt, m);
  }
  __shared__ float s1[16], s2[16];
  if ((t & 63) == 0) { s1[t >> 6] = ls; s2[t >> 6] = cnt; }
  __syncthreads();
  if (t == 0) {
    float T = 0.f, C = 0.f;
    for (int i = 0; i < 16; ++i) { T += s1[i]; C += s2[i]; }
    out[0] = (C > 0.f) ? T / C : 0.f;
  }
}

extern "C" void kernel_launch(void* const* d_in, const int* in_sizes, int n_in,
                              void* d_out, int out_size, void* d_ws, size_t ws_size,
                              hipStream_t stream) {
  const float* feat = (const float*)d_in[0];
  const long long* et = (const long long*)d_in[1];
  char* ws = (char*)d_ws;
  u16* fbf      = (u16*)(ws + OFF_FBF);
  float* sum_e  = (float*)(ws + OFF_SUME);
  float* pos_s  = (float*)(ws + OFF_POSS);
  int* hist     = (int*)(ws + OFF_HIST);
  int* types    = (int*)(ws + OFF_TYPE);
  float* out    = (float*)d_out;

  k_zero<<<(ZERO_WORDS + 255) / 256, 256, 0, stream>>>(sum_e, ZERO_WORDS);
  k_norm<<<N / 4, 256, 0, stream>>>(feat, et, fbf, types, hist);
  k_gemm<<<NTRI, 512, 0, stream>>>(fbf, types, sum_e, pos_s);
  k_final<<<1, 1024, 0, stream>>>(sum_e, pos_s, types, hist, out);
}